// Round 8
// baseline (440.685 us; speedup 1.0000x reference)
//
#include <hip/hip_runtime.h>

#define F 128
#define NN 100000
#define NBUK 782   // ceil(NN/128), 128 nodes per bucket = one sage block
#define NBLK 256   // scatter chunks (~16-edge = 64B runs per (blk,bucket))
#define LD 136     // padded LDS row stride in bf16 elems (272 B)
#define N4 (NN * F / 4)   // 3.2M float4's in x
#define N4A (N4 / 2)      // cvt half in K1, half in K2

typedef __attribute__((ext_vector_type(8))) short short8;   // 8 bf16 = 16 B
typedef __attribute__((ext_vector_type(4))) float f32x4;
typedef __attribute__((ext_vector_type(4))) unsigned short us4;
typedef unsigned short ushort_t;

// ---------------------------------------------------------------------------
// bf16 helpers (RNE)
// ---------------------------------------------------------------------------
__device__ __forceinline__ ushort_t f2b(float f) {
    union { float f; unsigned u; } x;
    x.f = f;
    unsigned r = x.u + 0x7fffu + ((x.u >> 16) & 1u);
    return (ushort_t)(r >> 16);
}
__device__ __forceinline__ float b2f(ushort_t u) {
    union { unsigned u; float f; } x;
    x.u = ((unsigned)u) << 16;
    return x.f;
}

// ---------------------------------------------------------------------------
// K1 (fused): [0,NBLK): chunk bucket histogram -> H[blk][NBUK]
//             [NBLK,NBLK+64): W -> WT bf16 transpose (4 matrices)
//             [NBLK+64,...): x -> bf16, first half
// ---------------------------------------------------------------------------
__global__ __launch_bounds__(256) void k1_fused(
    const int* __restrict__ dst, int* __restrict__ H, int E, int chunk,
    const float* __restrict__ Wa, const float* __restrict__ Wb,
    const float* __restrict__ Wc, const float* __restrict__ Wd,
    ushort_t* __restrict__ Oa, ushort_t* __restrict__ Ob,
    ushort_t* __restrict__ Oc, ushort_t* __restrict__ Od,
    const float* __restrict__ X, ushort_t* __restrict__ Y) {
    __shared__ union {
        int h[NBUK];
        float tile[32][33];
    } u;
    const int blk = blockIdx.x;
    if (blk < NBLK) {
        for (int i = threadIdx.x; i < NBUK; i += 256) u.h[i] = 0;
        __syncthreads();
        const int s0 = blk * chunk, s1 = min(E, s0 + chunk);
        for (int i = s0 + threadIdx.x; i < s1; i += 256)
            atomicAdd(&u.h[dst[i] >> 7], 1);
        __syncthreads();
        for (int i = threadIdx.x; i < NBUK; i += 256)
            H[blk * NBUK + i] = u.h[i];
    } else if (blk < NBLK + 64) {
        const int m = (blk - NBLK) >> 4;
        const int b = (blk - NBLK) & 15;
        const float* W = (m == 0) ? Wa : (m == 1) ? Wb : (m == 2) ? Wc : Wd;
        ushort_t* WT = (m == 0) ? Oa : (m == 1) ? Ob : (m == 2) ? Oc : Od;
        const int by = (b >> 2) * 32;
        const int bx = (b & 3) * 32;
        const int tx = threadIdx.x & 31, ty = threadIdx.x >> 5;
        for (int i = 0; i < 32; i += 8)
            u.tile[ty + i][tx] = W[(by + ty + i) * F + bx + tx];
        __syncthreads();
        for (int i = 0; i < 32; i += 8)
            WT[(bx + ty + i) * F + by + tx] = f2b(u.tile[tx][ty + i]);
    } else {
        const int i = (blk - NBLK - 64) * 256 + threadIdx.x;
        if (i < N4A) {
            float4 v = ((const float4*)X)[i];
            us4 o;
            o.x = f2b(v.x); o.y = f2b(v.y); o.z = f2b(v.z); o.w = f2b(v.w);
            ((us4*)Y)[i] = o;
        }
    }
}

// ---------------------------------------------------------------------------
// K2 (fused, 1024 thr): block 0: column-scan H + bucket-total scan -> boffs
//                       blocks >=1: cvt second half
// ---------------------------------------------------------------------------
__global__ __launch_bounds__(1024) void k2_fused(
    int* __restrict__ H, int* __restrict__ boffs, int E,
    const float* __restrict__ X, ushort_t* __restrict__ Y) {
    if (blockIdx.x == 0) {
        __shared__ int tot[1024];
        const int k = threadIdx.x;
        int sum = 0;
        if (k < NBUK) {
#pragma unroll 1
            for (int b = 0; b < NBLK; b += 4) {
                const int v0 = H[(b + 0) * NBUK + k];
                const int v1 = H[(b + 1) * NBUK + k];
                const int v2 = H[(b + 2) * NBUK + k];
                const int v3 = H[(b + 3) * NBUK + k];
                H[(b + 0) * NBUK + k] = sum; sum += v0;
                H[(b + 1) * NBUK + k] = sum; sum += v1;
                H[(b + 2) * NBUK + k] = sum; sum += v2;
                H[(b + 3) * NBUK + k] = sum; sum += v3;
            }
        }
        tot[k] = (k < NBUK) ? sum : 0;
        __syncthreads();
        for (int d = 1; d < 1024; d <<= 1) {
            const int u = (k >= d) ? tot[k - d] : 0;
            __syncthreads();
            tot[k] += u;
            __syncthreads();
        }
        if (k < NBUK) boffs[k] = tot[k] - sum;
        if (k == 0) boffs[NBUK] = E;
    } else {
        const int i = N4A + (blockIdx.x - 1) * 1024 + threadIdx.x;
        if (i < N4) {
            float4 v = ((const float4*)X)[i];
            us4 o;
            o.x = f2b(v.x); o.y = f2b(v.y); o.z = f2b(v.z); o.w = f2b(v.w);
            ((us4*)Y)[i] = o;
        }
    }
}

// ---------------------------------------------------------------------------
// scatter packed (dstlo<<20 | src) via LDS cursors into bucket regions.
// ---------------------------------------------------------------------------
__global__ __launch_bounds__(256) void scatter2(const int* __restrict__ src,
                                                const int* __restrict__ dst,
                                                const int* __restrict__ H,
                                                const int* __restrict__ boffs,
                                                unsigned* __restrict__ pairs,
                                                int E, int chunk) {
    __shared__ int cur[NBUK];
    const int b = blockIdx.x;
    for (int i = threadIdx.x; i < NBUK; i += 256)
        cur[i] = boffs[i] + H[b * NBUK + i];
    __syncthreads();
    const int s0 = b * chunk, s1 = min(E, s0 + chunk);
    for (int i = s0 + threadIdx.x; i < s1; i += 256) {
        const int d = dst[i];
        const int p = atomicAdd(&cur[d >> 7], 1);
        pairs[p] = ((unsigned)(d & 127) << 20) | (unsigned)src[i];
    }
}

// ---------------------------------------------------------------------------
// sage_bucket: block = one 128-row bucket, 1024 thr = 16 waves, dynamic
// ticket queue over 782 buckets (persistent 512-block grid).
// Preamble: per-row count + LDS scan (+ csr fill when DOFILL).
// Phase A: 64 slots x 16 lanes gather-mean -> sH (registers, 4-deep MLP).
// Phase B: 16 waves x (32row x 32col) MFMA tiles.
// LDS ~71 KB -> 2 blocks/CU (32 waves).
// ---------------------------------------------------------------------------
template <typename TOUT, int DOFILL, int RELU>
__global__ __launch_bounds__(1024, 8) void sage_bucket(
    const ushort_t* __restrict__ Xg,
    const unsigned* __restrict__ pairs,
    const int* __restrict__ boffs,
    int* __restrict__ csr,
    const ushort_t* __restrict__ WTs, const ushort_t* __restrict__ WTn,
    const float* __restrict__ bias,
    TOUT* __restrict__ out,
    int* __restrict__ ticket) {
    __shared__ __align__(16) ushort_t sX[128 * LD];  // 34816 B
    __shared__ __align__(16) ushort_t sH[128 * LD];  // 34816 B
    __shared__ int cnt[128], loffs[128], lcur[128];
    __shared__ int sTile;

    const int t = threadIdx.x;
    const int lane = t & 63;
    const int wave = t >> 6;

    for (;;) {
        if (t == 0) sTile = atomicAdd(ticket, 1);
        __syncthreads();
        const int buk = sTile;
        __syncthreads();  // protect sTile before next overwrite
        if (buk >= NBUK) break;

        const int brow0 = buk << 7;
        const int nnode = min(128, NN - brow0);
        const int e0 = boffs[buk], e1 = boffs[buk + 1];

        // ---- preamble: per-row count + scan (+ csr fill for layer 1) ----
        if (t < 128) cnt[t] = 0;
        __syncthreads();
        for (int i = e0 + t; i < e1; i += 1024)
            atomicAdd(&cnt[pairs[i] >> 20], 1);
        __syncthreads();
        if (t < 128) loffs[t] = cnt[t];
        __syncthreads();
        for (int d = 1; d < 128; d <<= 1) {
            const int u = (t < 128 && t >= d) ? loffs[t - d] : 0;
            __syncthreads();
            if (t < 128) loffs[t] += u;
            __syncthreads();
        }
        if (t < 128) {
            const int st = e0 + loffs[t] - cnt[t];  // row start (exclusive)
            loffs[t] = st;
            lcur[t] = st;
        }
        __syncthreads();
        if (DOFILL) {
            for (int i = e0 + t; i < e1; i += 1024) {
                const unsigned v = pairs[i];
                const int p = atomicAdd(&lcur[v >> 20], 1);
                csr[p] = (int)(v & 0xFFFFFu);
            }
        }

        // ---- phase 0: stage self rows (overlaps csr fill drain) ----
        {
            const ushort_t* base = Xg + (size_t)brow0 * F;
            for (int i = t; i < 128 * 16; i += 1024) {
                const int row = i >> 4, ch = i & 15;
                *(short8*)&sX[row * LD + ch * 8] = *(const short8*)&base[row * F + ch * 8];
            }
        }
        __syncthreads();  // csr stores drained + visible; sX ready

        // ---- phase A: neighbor mean -> sH (64 slots x 2 rows) ----
        {
            const int slot = t >> 4;
            const int c8 = (t & 15) * 8;
#pragma unroll
            for (int rr = 0; rr < 2; rr++) {
                const int r = slot * 2 + rr;
                const int es = loffs[r];
                const int n = cnt[r];
                const int ee = es + n;
                float a0[8], a1[8], a2[8], a3[8];
#pragma unroll
                for (int j = 0; j < 8; j++) { a0[j] = a1[j] = a2[j] = a3[j] = 0.f; }
                int e = es;
                for (; e + 3 < ee; e += 4) {
                    const int s0 = csr[e], s1 = csr[e + 1], s2 = csr[e + 2], s3 = csr[e + 3];
                    const short8 v0 = *(const short8*)&Xg[(size_t)s0 * F + c8];
                    const short8 v1 = *(const short8*)&Xg[(size_t)s1 * F + c8];
                    const short8 v2 = *(const short8*)&Xg[(size_t)s2 * F + c8];
                    const short8 v3 = *(const short8*)&Xg[(size_t)s3 * F + c8];
#pragma unroll
                    for (int j = 0; j < 8; j++) {
                        a0[j] += b2f((ushort_t)v0[j]);
                        a1[j] += b2f((ushort_t)v1[j]);
                        a2[j] += b2f((ushort_t)v2[j]);
                        a3[j] += b2f((ushort_t)v3[j]);
                    }
                }
                for (; e < ee; e++) {
                    const int s0 = csr[e];
                    const short8 v0 = *(const short8*)&Xg[(size_t)s0 * F + c8];
#pragma unroll
                    for (int j = 0; j < 8; j++) a0[j] += b2f((ushort_t)v0[j]);
                }
                const float inv = (n > 0) ? (1.0f / (float)n) : 0.f;
                short8 o;
#pragma unroll
                for (int j = 0; j < 8; j++)
                    o[j] = (short)f2b(((a0[j] + a1[j]) + (a2[j] + a3[j])) * inv);
                *(short8*)&sH[r * LD + c8] = o;
            }
        }
        __syncthreads();

        // ---- phase B: MFMA (wave (rg,cg): rows rg*32.., cols cg*32..) ----
        const int q = lane >> 4, nl = lane & 15;
        const int rg = wave & 3, cg = wave >> 2;
        const int rbase = rg * 32;
        const int colbase = cg * 32;
        f32x4 acc00 = (f32x4)0.f, acc01 = (f32x4)0.f, acc10 = (f32x4)0.f, acc11 = (f32x4)0.f;
#pragma unroll
        for (int ks = 0; ks < 4; ks++) {
            const int ko = ks * 32 + q * 8;
            const short8 aS0 = *(const short8*)&sX[(rbase + nl) * LD + ko];
            const short8 aS1 = *(const short8*)&sX[(rbase + 16 + nl) * LD + ko];
            const short8 aN0 = *(const short8*)&sH[(rbase + nl) * LD + ko];
            const short8 aN1 = *(const short8*)&sH[(rbase + 16 + nl) * LD + ko];
            const size_t bo0 = (size_t)(colbase + nl) * F + ko;
            const size_t bo1 = (size_t)(colbase + 16 + nl) * F + ko;
            const short8 bS0 = *(const short8*)&WTs[bo0];
            const short8 bS1 = *(const short8*)&WTs[bo1];
            const short8 bN0 = *(const short8*)&WTn[bo0];
            const short8 bN1 = *(const short8*)&WTn[bo1];
            acc00 = __builtin_amdgcn_mfma_f32_16x16x32_bf16(aS0, bS0, acc00, 0, 0, 0);
            acc00 = __builtin_amdgcn_mfma_f32_16x16x32_bf16(aN0, bN0, acc00, 0, 0, 0);
            acc01 = __builtin_amdgcn_mfma_f32_16x16x32_bf16(aS0, bS1, acc01, 0, 0, 0);
            acc01 = __builtin_amdgcn_mfma_f32_16x16x32_bf16(aN0, bN1, acc01, 0, 0, 0);
            acc10 = __builtin_amdgcn_mfma_f32_16x16x32_bf16(aS1, bS0, acc10, 0, 0, 0);
            acc10 = __builtin_amdgcn_mfma_f32_16x16x32_bf16(aN1, bN0, acc10, 0, 0, 0);
            acc11 = __builtin_amdgcn_mfma_f32_16x16x32_bf16(aS1, bS1, acc11, 0, 0, 0);
            acc11 = __builtin_amdgcn_mfma_f32_16x16x32_bf16(aN1, bN1, acc11, 0, 0, 0);
        }

        // ---- epilogue: C/D layout col=lane&15, row=(lane>>4)*4+reg ----
        const float b0 = bias[colbase + nl];
        const float b1 = bias[colbase + 16 + nl];
        if constexpr (sizeof(TOUT) == 2) {
            __syncthreads();  // all waves done reading sX
#pragma unroll
            for (int r = 0; r < 4; r++) {
                const int lr0 = rbase + q * 4 + r, lr1 = rbase + 16 + q * 4 + r;
                float v00 = acc00[r] + b0, v01 = acc01[r] + b1;
                float v10 = acc10[r] + b0, v11 = acc11[r] + b1;
                if (RELU) {
                    v00 = fmaxf(v00, 0.f); v01 = fmaxf(v01, 0.f);
                    v10 = fmaxf(v10, 0.f); v11 = fmaxf(v11, 0.f);
                }
                sX[lr0 * LD + colbase + nl] = f2b(v00);
                sX[lr0 * LD + colbase + 16 + nl] = f2b(v01);
                sX[lr1 * LD + colbase + nl] = f2b(v10);
                sX[lr1 * LD + colbase + 16 + nl] = f2b(v11);
            }
            __syncthreads();
            TOUT* base = out + (size_t)brow0 * F;
            for (int i = t; i < 128 * 16; i += 1024) {
                const int row = i >> 4, ch = i & 15;
                if (row < nnode)
                    *(short8*)&base[row * F + ch * 8] = *(const short8*)&sX[row * LD + ch * 8];
            }
        } else {
#pragma unroll
            for (int r = 0; r < 4; r++) {
                const int orow0 = brow0 + rbase + q * 4 + r;
                const int orow1 = brow0 + rbase + 16 + q * 4 + r;
                float v00 = acc00[r] + b0, v01 = acc01[r] + b1;
                float v10 = acc10[r] + b0, v11 = acc11[r] + b1;
                if (RELU) {
                    v00 = fmaxf(v00, 0.f); v01 = fmaxf(v01, 0.f);
                    v10 = fmaxf(v10, 0.f); v11 = fmaxf(v11, 0.f);
                }
                if (orow0 < NN) {
                    out[(size_t)orow0 * F + colbase + nl] = v00;
                    out[(size_t)orow0 * F + colbase + 16 + nl] = v01;
                }
                if (orow1 < NN) {
                    out[(size_t)orow1 * F + colbase + nl] = v10;
                    out[(size_t)orow1 * F + colbase + 16 + nl] = v11;
                }
            }
        }
        __syncthreads();  // LDS safe to reuse for next tile
    }
}

// ---------------------------------------------------------------------------
extern "C" void kernel_launch(void* const* d_in, const int* in_sizes, int n_in,
                              void* d_out, int out_size, void* d_ws, size_t ws_size,
                              hipStream_t stream) {
    const float* x = (const float*)d_in[0];
    const int* src = (const int*)d_in[1];
    const int* dst = (const int*)d_in[2];
    const float* W1s = (const float*)d_in[3];
    const float* W1n = (const float*)d_in[4];
    const float* b1 = (const float*)d_in[5];
    const float* W2s = (const float*)d_in[6];
    const float* W2n = (const float*)d_in[7];
    const float* b2 = (const float*)d_in[8];
    float* out = (float*)d_out;

    const int E = in_sizes[1];
    const int N = NN;
    const int E4 = (E + 3) & ~3;
    const int chunk = (E + NBLK - 1) / NBLK;

    // ws layout (~40 MB < proven-safe budget):
    //   pairs[E] | csr[E] | h1[N*F] bf16 | WT 4*F*F bf16 | H[NBLK*NBUK] |
    //   boffs[NBUK+1] | tickets[2]
    unsigned* pairs = (unsigned*)d_ws;
    int* csr = (int*)(pairs + E4);
    ushort_t* h1 = (ushort_t*)(csr + E4);
    ushort_t* WT1s = h1 + (size_t)N * F;
    ushort_t* WT1n = WT1s + F * F;
    ushort_t* WT2s = WT1n + F * F;
    ushort_t* WT2n = WT2s + F * F;
    int* H = (int*)(WT2n + F * F);
    int* boffs = H + NBLK * NBUK;
    int* tickets = boffs + (NBUK + 1);
    // x_bf16 lives in d_out: dead by the time layer 2 overwrites d_out.
    ushort_t* xb = (ushort_t*)d_out;

    hipMemsetAsync(tickets, 0, 2 * sizeof(int), stream);

    // K1: hist + weight transpose + cvt half A
    const int cvtA_blocks = (N4A + 255) / 256;
    k1_fused<<<NBLK + 64 + cvtA_blocks, 256, 0, stream>>>(
        dst, H, E, chunk, W1s, W1n, W2s, W2n, WT1s, WT1n, WT2s, WT2n, x, xb);
    // K2: scan + cvt half B
    const int cvtB_blocks = (N4 - N4A + 1023) / 1024;
    k2_fused<<<1 + cvtB_blocks, 1024, 0, stream>>>(H, boffs, E, x, xb);
    scatter2<<<NBLK, 256, 0, stream>>>(src, dst, H, boffs, pairs, E, chunk);

    // layer 1: bf16 in (xb), bf16 h1 out, relu; fills csr
    sage_bucket<ushort_t, 1, 1><<<512, 1024, 0, stream>>>(
        xb, pairs, boffs, csr, WT1s, WT1n, b1, h1, &tickets[0]);
    // layer 2: bf16 in (h1), fp32 out; reuses csr
    sage_bucket<float, 0, 0><<<512, 1024, 0, stream>>>(
        h1, pairs, boffs, csr, WT2s, WT2n, b2, out, &tickets[1]);
}

// Round 9
// 348.773 us; speedup vs baseline: 1.2635x; 1.2635x over previous
//
#include <hip/hip_runtime.h>

#define F 128
#define NN 100000
#define NBUK 782   // ceil(NN/128), 128 nodes per bucket
#define NBLK 256   // sort chunks
#define LD 136     // padded LDS row stride in bf16 elems (272 B)
#define N4 (NN * F / 4)   // 3.2M float4's in x
#define N4A (N4 / 2)      // cvt half in K1, half in K2

typedef __attribute__((ext_vector_type(8))) short short8;   // 8 bf16 = 16 B
typedef __attribute__((ext_vector_type(4))) float f32x4;
typedef __attribute__((ext_vector_type(4))) unsigned short us4;
typedef unsigned short ushort_t;

// ---------------------------------------------------------------------------
// bf16 helpers (RNE)
// ---------------------------------------------------------------------------
__device__ __forceinline__ ushort_t f2b(float f) {
    union { float f; unsigned u; } x;
    x.f = f;
    unsigned r = x.u + 0x7fffu + ((x.u >> 16) & 1u);
    return (ushort_t)(r >> 16);
}
__device__ __forceinline__ float b2f(ushort_t u) {
    union { unsigned u; float f; } x;
    x.u = ((unsigned)u) << 16;
    return x.f;
}

// ---------------------------------------------------------------------------
// K1 (fused): [0,NBLK): chunk bucket histogram -> H[blk][NBUK]
//             [NBLK,NBLK+64): W -> WT bf16 transpose (4 matrices)
//             [NBLK+64,...): x -> bf16, first half
// ---------------------------------------------------------------------------
__global__ __launch_bounds__(256) void k1_fused(
    const int* __restrict__ dst, int* __restrict__ H, int E, int chunk,
    const float* __restrict__ Wa, const float* __restrict__ Wb,
    const float* __restrict__ Wc, const float* __restrict__ Wd,
    ushort_t* __restrict__ Oa, ushort_t* __restrict__ Ob,
    ushort_t* __restrict__ Oc, ushort_t* __restrict__ Od,
    const float* __restrict__ X, ushort_t* __restrict__ Y) {
    __shared__ union {
        int h[NBUK];
        float tile[32][33];
    } u;
    const int blk = blockIdx.x;
    if (blk < NBLK) {
        for (int i = threadIdx.x; i < NBUK; i += 256) u.h[i] = 0;
        __syncthreads();
        const int s0 = blk * chunk, s1 = min(E, s0 + chunk);
        for (int i = s0 + threadIdx.x; i < s1; i += 256)
            atomicAdd(&u.h[dst[i] >> 7], 1);
        __syncthreads();
        for (int i = threadIdx.x; i < NBUK; i += 256)
            H[blk * NBUK + i] = u.h[i];
    } else if (blk < NBLK + 64) {
        const int m = (blk - NBLK) >> 4;
        const int b = (blk - NBLK) & 15;
        const float* W = (m == 0) ? Wa : (m == 1) ? Wb : (m == 2) ? Wc : Wd;
        ushort_t* WT = (m == 0) ? Oa : (m == 1) ? Ob : (m == 2) ? Oc : Od;
        const int by = (b >> 2) * 32;
        const int bx = (b & 3) * 32;
        const int tx = threadIdx.x & 31, ty = threadIdx.x >> 5;
        for (int i = 0; i < 32; i += 8)
            u.tile[ty + i][tx] = W[(by + ty + i) * F + bx + tx];
        __syncthreads();
        for (int i = 0; i < 32; i += 8)
            WT[(bx + ty + i) * F + by + tx] = f2b(u.tile[tx][ty + i]);
    } else {
        const int i = (blk - NBLK - 64) * 256 + threadIdx.x;
        if (i < N4A) {
            float4 v = ((const float4*)X)[i];
            us4 o;
            o.x = f2b(v.x); o.y = f2b(v.y); o.z = f2b(v.z); o.w = f2b(v.w);
            ((us4*)Y)[i] = o;
        }
    }
}

// ---------------------------------------------------------------------------
// scan_cols: block k = bucket k; parallel LDS scan of H[:,k] over NBLK chunks
// (replaces round-7's 256-long serial dependent-load chain on one block).
// H[b][k] becomes block-b's exclusive offset within bucket k; Htot[k] = total.
// ---------------------------------------------------------------------------
__global__ __launch_bounds__(256) void scan_cols(int* __restrict__ H,
                                                 int* __restrict__ Htot) {
    __shared__ int s[NBLK];
    const int k = blockIdx.x;
    const int t = threadIdx.x;
    const int v = H[t * NBUK + k];
    s[t] = v;
    __syncthreads();
    for (int d = 1; d < NBLK; d <<= 1) {
        const int u = (t >= d) ? s[t - d] : 0;
        __syncthreads();
        s[t] += u;
        __syncthreads();
    }
    H[t * NBUK + k] = s[t] - v;  // exclusive
    if (t == NBLK - 1) Htot[k] = s[t];
}

// ---------------------------------------------------------------------------
// K2 (fused, 1024 thr): block 0: scan of 782 bucket totals -> boffs
//                       blocks >=1: cvt second half
// ---------------------------------------------------------------------------
__global__ __launch_bounds__(1024) void k2_fused(
    const int* __restrict__ Htot, int* __restrict__ boffs, int E,
    const float* __restrict__ X, ushort_t* __restrict__ Y) {
    if (blockIdx.x == 0) {
        __shared__ int tot[1024];
        const int k = threadIdx.x;
        const int v = (k < NBUK) ? Htot[k] : 0;
        tot[k] = v;
        __syncthreads();
        for (int d = 1; d < 1024; d <<= 1) {
            const int u = (k >= d) ? tot[k - d] : 0;
            __syncthreads();
            tot[k] += u;
            __syncthreads();
        }
        if (k < NBUK) boffs[k] = tot[k] - v;  // exclusive base
        if (k == 0) boffs[NBUK] = E;
    } else {
        const int i = N4A + (blockIdx.x - 1) * 1024 + threadIdx.x;
        if (i < N4) {
            float4 v = ((const float4*)X)[i];
            us4 o;
            o.x = f2b(v.x); o.y = f2b(v.y); o.z = f2b(v.z); o.w = f2b(v.w);
            ((us4*)Y)[i] = o;
        }
    }
}

// ---------------------------------------------------------------------------
// scatter packed (dstlo<<20 | src) via LDS cursors into bucket regions.
// ---------------------------------------------------------------------------
__global__ __launch_bounds__(256) void scatter2(const int* __restrict__ src,
                                                const int* __restrict__ dst,
                                                const int* __restrict__ H,
                                                const int* __restrict__ boffs,
                                                unsigned* __restrict__ pairs,
                                                int E, int chunk) {
    __shared__ int cur[NBUK];
    const int b = blockIdx.x;
    for (int i = threadIdx.x; i < NBUK; i += 256)
        cur[i] = boffs[i] + H[b * NBUK + i];
    __syncthreads();
    const int s0 = b * chunk, s1 = min(E, s0 + chunk);
    for (int i = s0 + threadIdx.x; i < s1; i += 256) {
        const int d = dst[i];
        const int p = atomicAdd(&cur[d >> 7], 1);
        pairs[p] = ((unsigned)(d & 127) << 20) | (unsigned)src[i];
    }
}

// ---------------------------------------------------------------------------
// per-bucket counting sort in LDS; csr/offs writes sequential.
// ---------------------------------------------------------------------------
__global__ __launch_bounds__(256) void bucket_sort(const unsigned* __restrict__ pairs,
                                                   const int* __restrict__ boffs,
                                                   int* __restrict__ offs,
                                                   int* __restrict__ csr) {
    __shared__ int cnt[128], loffs[128], lcur[128];
    const int b = blockIdx.x, t = threadIdx.x;
    const int e0 = boffs[b], e1 = boffs[b + 1];
    const int node0 = b << 7;
    const int nnode = min(128, NN - node0);
    if (t < 128) cnt[t] = 0;
    __syncthreads();
    for (int i = e0 + t; i < e1; i += 256) atomicAdd(&cnt[pairs[i] >> 20], 1);
    __syncthreads();
    if (t < 128) loffs[t] = cnt[t];
    __syncthreads();
    for (int d = 1; d < 128; d <<= 1) {
        int u = (t >= d && t < 128) ? loffs[t - d] : 0;
        __syncthreads();
        if (t < 128) loffs[t] += u;
        __syncthreads();
    }
    if (t < 128) {
        const int ex = loffs[t] - cnt[t];  // exclusive
        lcur[t] = e0 + ex;
        if (t < nnode) offs[node0 + t] = e0 + ex;
    }
    if (b == NBUK - 1 && t == 0) offs[NN] = e1;
    __syncthreads();
    for (int i = e0 + t; i < e1; i += 256) {
        const unsigned v = pairs[i];
        const int p = atomicAdd(&lcur[v >> 20], 1);
        csr[p] = (int)(v & 0xFFFFFu);
    }
}

// ---------------------------------------------------------------------------
// fused SAGE layer (bf16 MFMA) — round-7 proven version, verbatim.
// 8 blocks/CU; bf16 output bounces through LDS for coalesced row stores.
// ---------------------------------------------------------------------------
template <typename TOUT>
__global__ __launch_bounds__(256, 8) void sage_layer(
    const ushort_t* __restrict__ Xg,
    const int* __restrict__ offs, const int* __restrict__ csr,
    const ushort_t* __restrict__ WTs, const ushort_t* __restrict__ WTn,
    const float* __restrict__ bias,
    TOUT* __restrict__ out, int relu) {
    __shared__ __align__(16) ushort_t sX[32 * LD];
    __shared__ __align__(16) ushort_t sH[32 * LD];
    const int t = threadIdx.x;
    const int lane = t & 63;
    const int wave = t >> 6;
    const int brow0 = blockIdx.x * 32;

    // Phase 0: stage self rows
    {
        const ushort_t* base = Xg + (size_t)brow0 * F;
        for (int i = t; i < 32 * 16; i += 256) {
            int row = i >> 4, ch = i & 15;
            *(short8*)&sX[row * LD + ch * 8] = *(const short8*)&base[row * F + ch * 8];
        }
    }

    // Phase A: neighbor mean -> sH (4 slots x 16 lanes; unroll 4)
    {
        const int slot = lane >> 4;
        const int cl = lane & 15;
        const int c8 = cl * 8;
#pragma unroll
        for (int rr = 0; rr < 2; rr++) {
            const int rloc = wave * 8 + slot * 2 + rr;
            const int row = brow0 + rloc;
            const int e0 = offs[row], e1 = offs[row + 1];
            float a0[8], a1[8], a2[8], a3[8];
#pragma unroll
            for (int j = 0; j < 8; j++) { a0[j] = a1[j] = a2[j] = a3[j] = 0.f; }
            int e = e0;
            for (; e + 3 < e1; e += 4) {
                const int s0 = csr[e], s1 = csr[e + 1], s2 = csr[e + 2], s3 = csr[e + 3];
                const short8 v0 = *(const short8*)&Xg[(size_t)s0 * F + c8];
                const short8 v1 = *(const short8*)&Xg[(size_t)s1 * F + c8];
                const short8 v2 = *(const short8*)&Xg[(size_t)s2 * F + c8];
                const short8 v3 = *(const short8*)&Xg[(size_t)s3 * F + c8];
#pragma unroll
                for (int j = 0; j < 8; j++) {
                    a0[j] += b2f((ushort_t)v0[j]);
                    a1[j] += b2f((ushort_t)v1[j]);
                    a2[j] += b2f((ushort_t)v2[j]);
                    a3[j] += b2f((ushort_t)v3[j]);
                }
            }
            for (; e < e1; e++) {
                const int s0 = csr[e];
                const short8 v0 = *(const short8*)&Xg[(size_t)s0 * F + c8];
#pragma unroll
                for (int j = 0; j < 8; j++) a0[j] += b2f((ushort_t)v0[j]);
            }
            const float inv = (e1 > e0) ? (1.0f / (float)(e1 - e0)) : 0.f;
            short8 o;
#pragma unroll
            for (int j = 0; j < 8; j++)
                o[j] = (short)f2b(((a0[j] + a1[j]) + (a2[j] + a3[j])) * inv);
            *(short8*)&sH[rloc * LD + c8] = o;
        }
    }
    __syncthreads();

    // Phase B: MFMA GEMM (wave strip: 32 rows x 32 cols)
    const int q = lane >> 4, nl = lane & 15;
    const int colbase = wave * 32;
    f32x4 acc00 = (f32x4)0.f, acc01 = (f32x4)0.f, acc10 = (f32x4)0.f, acc11 = (f32x4)0.f;
#pragma unroll
    for (int ks = 0; ks < 4; ks++) {
        const int ko = ks * 32 + q * 8;
        const short8 aS0 = *(const short8*)&sX[nl * LD + ko];
        const short8 aS1 = *(const short8*)&sX[(16 + nl) * LD + ko];
        const short8 aN0 = *(const short8*)&sH[nl * LD + ko];
        const short8 aN1 = *(const short8*)&sH[(16 + nl) * LD + ko];
        const size_t bo0 = (size_t)(colbase + nl) * F + ko;
        const size_t bo1 = (size_t)(colbase + 16 + nl) * F + ko;
        const short8 bS0 = *(const short8*)&WTs[bo0];
        const short8 bS1 = *(const short8*)&WTs[bo1];
        const short8 bN0 = *(const short8*)&WTn[bo0];
        const short8 bN1 = *(const short8*)&WTn[bo1];
        acc00 = __builtin_amdgcn_mfma_f32_16x16x32_bf16(aS0, bS0, acc00, 0, 0, 0);
        acc00 = __builtin_amdgcn_mfma_f32_16x16x32_bf16(aN0, bN0, acc00, 0, 0, 0);
        acc01 = __builtin_amdgcn_mfma_f32_16x16x32_bf16(aS0, bS1, acc01, 0, 0, 0);
        acc01 = __builtin_amdgcn_mfma_f32_16x16x32_bf16(aN0, bN1, acc01, 0, 0, 0);
        acc10 = __builtin_amdgcn_mfma_f32_16x16x32_bf16(aS1, bS0, acc10, 0, 0, 0);
        acc10 = __builtin_amdgcn_mfma_f32_16x16x32_bf16(aN1, bN0, acc10, 0, 0, 0);
        acc11 = __builtin_amdgcn_mfma_f32_16x16x32_bf16(aS1, bS1, acc11, 0, 0, 0);
        acc11 = __builtin_amdgcn_mfma_f32_16x16x32_bf16(aN1, bN1, acc11, 0, 0, 0);
    }

    // Epilogue: C/D layout col=lane&15, row=(lane>>4)*4+reg
    const float b0 = bias[colbase + nl];
    const float b1 = bias[colbase + 16 + nl];
    if constexpr (sizeof(TOUT) == 2) {
        __syncthreads();  // all waves done reading sX in phase B
#pragma unroll
        for (int r = 0; r < 4; r++) {
            const int lr0 = q * 4 + r, lr1 = 16 + q * 4 + r;
            float v00 = acc00[r] + b0, v01 = acc01[r] + b1;
            float v10 = acc10[r] + b0, v11 = acc11[r] + b1;
            if (relu) {
                v00 = fmaxf(v00, 0.f); v01 = fmaxf(v01, 0.f);
                v10 = fmaxf(v10, 0.f); v11 = fmaxf(v11, 0.f);
            }
            sX[lr0 * LD + colbase + nl] = f2b(v00);
            sX[lr0 * LD + colbase + 16 + nl] = f2b(v01);
            sX[lr1 * LD + colbase + nl] = f2b(v10);
            sX[lr1 * LD + colbase + 16 + nl] = f2b(v11);
        }
        __syncthreads();
        TOUT* base = out + (size_t)brow0 * F;
        for (int i = t; i < 32 * 16; i += 256) {
            int row = i >> 4, ch = i & 15;
            *(short8*)&base[row * F + ch * 8] = *(const short8*)&sX[row * LD + ch * 8];
        }
    } else {
#pragma unroll
        for (int r = 0; r < 4; r++) {
            const int orow0 = brow0 + q * 4 + r;
            const int orow1 = brow0 + 16 + q * 4 + r;
            float v00 = acc00[r] + b0, v01 = acc01[r] + b1;
            float v10 = acc10[r] + b0, v11 = acc11[r] + b1;
            if (relu) {
                v00 = fmaxf(v00, 0.f); v01 = fmaxf(v01, 0.f);
                v10 = fmaxf(v10, 0.f); v11 = fmaxf(v11, 0.f);
            }
            out[(size_t)orow0 * F + colbase + nl] = v00;
            out[(size_t)orow0 * F + colbase + 16 + nl] = v01;
            out[(size_t)orow1 * F + colbase + nl] = v10;
            out[(size_t)orow1 * F + colbase + 16 + nl] = v11;
        }
    }
}

// ---------------------------------------------------------------------------
extern "C" void kernel_launch(void* const* d_in, const int* in_sizes, int n_in,
                              void* d_out, int out_size, void* d_ws, size_t ws_size,
                              hipStream_t stream) {
    const float* x = (const float*)d_in[0];
    const int* src = (const int*)d_in[1];
    const int* dst = (const int*)d_in[2];
    const float* W1s = (const float*)d_in[3];
    const float* W1n = (const float*)d_in[4];
    const float* b1 = (const float*)d_in[5];
    const float* W2s = (const float*)d_in[6];
    const float* W2n = (const float*)d_in[7];
    const float* b2 = (const float*)d_in[8];
    float* out = (float*)d_out;

    const int E = in_sizes[1];
    const int N = NN;
    const int E4 = (E + 3) & ~3;
    const int chunk = (E + NBLK - 1) / NBLK;

    // ws layout (~40 MB < proven-safe budget):
    //   pairs[E] | csr[E] | h1[N*F] bf16 | WT 4*F*F bf16 |
    //   offs[N+1] | H[NBLK*NBUK] | boffs[NBUK+1] | Htot[NBUK]
    unsigned* pairs = (unsigned*)d_ws;
    int* csr = (int*)(pairs + E4);
    ushort_t* h1 = (ushort_t*)(csr + E4);
    ushort_t* WT1s = h1 + (size_t)N * F;
    ushort_t* WT1n = WT1s + F * F;
    ushort_t* WT2s = WT1n + F * F;
    ushort_t* WT2n = WT2s + F * F;
    int* offs = (int*)(WT2n + F * F);
    int* H = offs + (N + 1);
    int* boffs = H + NBLK * NBUK;
    int* Htot = boffs + (NBUK + 1);
    // x_bf16 lives in d_out: dead by the time layer 2 overwrites d_out.
    ushort_t* xb = (ushort_t*)d_out;

    // K1: hist + weight transpose + cvt half A
    const int cvtA_blocks = (N4A + 255) / 256;
    k1_fused<<<NBLK + 64 + cvtA_blocks, 256, 0, stream>>>(
        dst, H, E, chunk, W1s, W1n, W2s, W2n, WT1s, WT1n, WT2s, WT2n, x, xb);
    // parallel per-bucket column scan (replaces serial single-block scan)
    scan_cols<<<NBUK, NBLK, 0, stream>>>(H, Htot);
    // K2: bucket-total scan + cvt half B
    const int cvtB_blocks = (N4 - N4A + 1023) / 1024;
    k2_fused<<<1 + cvtB_blocks, 1024, 0, stream>>>(Htot, boffs, E, x, xb);
    scatter2<<<NBLK, 256, 0, stream>>>(src, dst, H, boffs, pairs, E, chunk);
    bucket_sort<<<NBUK, 256, 0, stream>>>(pairs, boffs, offs, csr);

    // layer 1: bf16 in (xb), bf16 h1 out, relu
    sage_layer<ushort_t><<<N / 32, 256, 0, stream>>>(
        xb, offs, csr, WT1s, WT1n, b1, h1, 1);
    // layer 2: bf16 in (h1), fp32 out
    sage_layer<float><<<N / 32, 256, 0, stream>>>(
        h1, offs, csr, WT2s, WT2n, b2, out, 0);
}